// Round 3
// baseline (6508.680 us; speedup 1.0000x reference)
//
#include <hip/hip_runtime.h>
#include <math.h>

#define T_LEN 4096
#define EMB 300
#define DIN 1200
#define HID 256
#define G4 1024           // 4*HID gate rows per direction
#define NTAG 12
#define START_TAG 10
#define STOP_TAG 11
#define NEGV -10000.0f

#if defined(__has_builtin)
#  if __has_builtin(__builtin_amdgcn_sdot4)
#    define HAVE_SDOT4 1
#  endif
#endif

__device__ __forceinline__ int sdot4(int a, int b, int c) {
#ifdef HAVE_SDOT4
  return __builtin_amdgcn_sdot4(a, b, c, false);
#else
  return c + (int)(char)(a) * (int)(char)(b)
           + (int)(char)(a >> 8) * (int)(char)(b >> 8)
           + (int)(char)(a >> 16) * (int)(char)(b >> 16)
           + (a >> 24) * (b >> 24);
#endif
}

__device__ __forceinline__ float sigm(float x) { return 1.0f / (1.0f + __expf(-x)); }
__device__ __forceinline__ float tanh_fast(float x) {
  x = fminf(fmaxf(x, -15.0f), 15.0f);
  float e = __expf(2.0f * x);
  return (e - 1.0f) / (e + 1.0f);
}

// ---------------------------------------------------------------------------
// Quantize w_hh (both directions) to int8, per-row scale.
// ---------------------------------------------------------------------------
__global__ __launch_bounds__(64) void quant_whh(const float* __restrict__ w_hh_f,
                                                const float* __restrict__ w_hh_b,
                                                int* __restrict__ qw,
                                                float* __restrict__ fac) {
  int row = blockIdx.x;   // 0..2047 (fwd rows 0..1023, bwd 1024..2047)
  int tid = threadIdx.x;  // 0..63
  const float* src = (row < G4) ? (w_hh_f + (size_t)row * HID)
                                : (w_hh_b + (size_t)(row - G4) * HID);
  float4 v = *(const float4*)(src + tid * 4);
  float m = fmaxf(fmaxf(fabsf(v.x), fabsf(v.y)), fmaxf(fabsf(v.z), fabsf(v.w)));
#pragma unroll
  for (int off = 32; off > 0; off >>= 1) m = fmaxf(m, __shfl_xor(m, off, 64));
  float inv = (m > 0.f) ? 127.0f / m : 0.f;
  int q0 = (int)rintf(v.x * inv), q1 = (int)rintf(v.y * inv);
  int q2 = (int)rintf(v.z * inv), q3 = (int)rintf(v.w * inv);
  qw[(size_t)row * 64 + tid] =
      (q0 & 255) | ((q1 & 255) << 8) | ((q2 & 255) << 16) | ((q3 & 255) << 24);
  if (tid == 0) fac[row] = m / (127.0f * 127.0f);
}

// ---------------------------------------------------------------------------
// xg[t][j] = emb_row(t) . w_ih[j] + b_ih[j] + b_hh[j];  j<1024 fwd, else bwd.
// ---------------------------------------------------------------------------
__global__ __launch_bounds__(256) void xg_gemm(
    const int* __restrict__ words0, const int* __restrict__ words1,
    const int* __restrict__ words2, const int* __restrict__ words3,
    const float* __restrict__ W_emb,
    const float* __restrict__ w_ih_f, const float* __restrict__ w_ih_b,
    const float* __restrict__ b_ih_f, const float* __restrict__ b_hh_f,
    const float* __restrict__ b_ih_b, const float* __restrict__ b_hh_b,
    float* __restrict__ xg) {
  __shared__ __align__(16) float As[16][132];
  __shared__ __align__(16) float Bs[16][68];
  __shared__ int w4[128][4];
  int tid = threadIdx.x;
  int t0 = blockIdx.x * 128;
  int n0 = blockIdx.y * 64;
  if (tid < 128) {
    int t = t0 + tid;
    w4[tid][0] = words0[t]; w4[tid][1] = words1[t];
    w4[tid][2] = words2[t]; w4[tid][3] = words3[t];
  }
  int kq = tid & 3;
  int r  = tid >> 2;
  const float* Bp = (n0 < G4) ? (w_ih_f + (size_t)(n0 + r) * DIN)
                              : (w_ih_b + (size_t)(n0 + r - G4) * DIN);
  float acc[8][4];
#pragma unroll
  for (int m = 0; m < 8; ++m)
#pragma unroll
    for (int n = 0; n < 4; ++n) acc[m][n] = 0.f;
  __syncthreads();

  for (int it = 0; it < 75; ++it) {
    int kk = it * 16 + kq * 4;
    int seg = (kk >= 900) ? 3 : (kk >= 600) ? 2 : (kk >= 300) ? 1 : 0;
    int col = kk - seg * 300;
    int wid0 = w4[r][seg];
    int wid1 = w4[r + 64][seg];
    float4 a0 = *(const float4*)(W_emb + (size_t)wid0 * EMB + col);
    float4 a1 = *(const float4*)(W_emb + (size_t)wid1 * EMB + col);
    float4 b  = *(const float4*)(Bp + kk);
    As[kq * 4 + 0][r] = a0.x; As[kq * 4 + 1][r] = a0.y;
    As[kq * 4 + 2][r] = a0.z; As[kq * 4 + 3][r] = a0.w;
    As[kq * 4 + 0][r + 64] = a1.x; As[kq * 4 + 1][r + 64] = a1.y;
    As[kq * 4 + 2][r + 64] = a1.z; As[kq * 4 + 3][r + 64] = a1.w;
    Bs[kq * 4 + 0][r] = b.x; Bs[kq * 4 + 1][r] = b.y;
    Bs[kq * 4 + 2][r] = b.z; Bs[kq * 4 + 3][r] = b.w;
    __syncthreads();
    int ii = (tid & 15) * 8;
    int jj = (tid >> 4) * 4;
#pragma unroll
    for (int k2 = 0; k2 < 16; ++k2) {
      float4 av0 = *(const float4*)&As[k2][ii];
      float4 av1 = *(const float4*)&As[k2][ii + 4];
      float4 bv  = *(const float4*)&Bs[k2][jj];
      float a[8] = {av0.x, av0.y, av0.z, av0.w, av1.x, av1.y, av1.z, av1.w};
      float bb[4] = {bv.x, bv.y, bv.z, bv.w};
#pragma unroll
      for (int m = 0; m < 8; ++m)
#pragma unroll
        for (int n = 0; n < 4; ++n) acc[m][n] = fmaf(a[m], bb[n], acc[m][n]);
    }
    __syncthreads();
  }
  int ii = (tid & 15) * 8;
  int jj = (tid >> 4) * 4;
  float bias[4];
#pragma unroll
  for (int n = 0; n < 4; ++n) {
    int jg = n0 + jj + n;
    bias[n] = (jg < G4) ? (b_ih_f[jg] + b_hh_f[jg])
                        : (b_ih_b[jg - G4] + b_hh_b[jg - G4]);
  }
#pragma unroll
  for (int m = 0; m < 8; ++m) {
    int row = t0 + ii + m;
    float4 st = make_float4(acc[m][0] + bias[0], acc[m][1] + bias[1],
                            acc[m][2] + bias[2], acc[m][3] + bias[3]);
    *(float4*)(xg + (size_t)row * 2048 + n0 + jj) = st;
  }
}

// ---------------------------------------------------------------------------
// LSTM recurrence v3. Same decomposition as v2 (512 thr, lane pair per
// hidden unit, half-K per thread as 32 named int4), but the weight values
// are PINNED with a zero-cost asm "+v" at the top of every iteration.
// Round-2 post-mortem: at VGPR_Count=88 the allocator had sunk the 32
// loop-invariant global_load_dwordx4 back into the loop ("spill to origin"),
// re-fetching 512 B/thread/step from L2. The pin makes the values opaque
// (asm may have changed them) so they MUST stay live in VGPRs; budget
// 128(w)+32(hv)+~35 misc < 256 cap from __launch_bounds__(512,2).
// Bit-identical numerics vs round 1/2.
// ---------------------------------------------------------------------------
#define D4(W, H, A)                                         \
  A = sdot4(W.x, H.x, A); A = sdot4(W.y, H.y, A);           \
  A = sdot4(W.z, H.z, A); A = sdot4(W.w, H.w, A);

#define PINI4(v) asm volatile("" : "+v"(v.x), "+v"(v.y), "+v"(v.z), "+v"(v.w))

__global__ __launch_bounds__(512, 2) void lstm_rec(
    const float* __restrict__ xg, const int* __restrict__ qw,
    const float* __restrict__ fac, float* __restrict__ hf,
    float* __restrict__ hb) {
  int dir = blockIdx.x;
  int tid = threadIdx.x;
  int k = tid >> 1;        // hidden unit 0..255
  int half = tid & 1;      // K-half 0..1 (partner lane is tid^1, same wave)
  __shared__ __align__(16) int hq[2][64];   // packed int8 h, double-buffered

  const int* wb0 = qw + (size_t)(dir * G4 + 0 * HID + k) * 64 + half * 32;
  const int* wb1 = qw + (size_t)(dir * G4 + 1 * HID + k) * 64 + half * 32;
  const int* wb2 = qw + (size_t)(dir * G4 + 2 * HID + k) * 64 + half * 32;
  const int* wb3 = qw + (size_t)(dir * G4 + 3 * HID + k) * 64 + half * 32;
  int4 w0a = *(const int4*)(wb0 + 0),  w0b = *(const int4*)(wb0 + 4);
  int4 w0c = *(const int4*)(wb0 + 8),  w0d = *(const int4*)(wb0 + 12);
  int4 w0e = *(const int4*)(wb0 + 16), w0f = *(const int4*)(wb0 + 20);
  int4 w0g = *(const int4*)(wb0 + 24), w0h = *(const int4*)(wb0 + 28);
  int4 w1a = *(const int4*)(wb1 + 0),  w1b = *(const int4*)(wb1 + 4);
  int4 w1c = *(const int4*)(wb1 + 8),  w1d = *(const int4*)(wb1 + 12);
  int4 w1e = *(const int4*)(wb1 + 16), w1f = *(const int4*)(wb1 + 20);
  int4 w1g = *(const int4*)(wb1 + 24), w1h = *(const int4*)(wb1 + 28);
  int4 w2a = *(const int4*)(wb2 + 0),  w2b = *(const int4*)(wb2 + 4);
  int4 w2c = *(const int4*)(wb2 + 8),  w2d = *(const int4*)(wb2 + 12);
  int4 w2e = *(const int4*)(wb2 + 16), w2f = *(const int4*)(wb2 + 20);
  int4 w2g = *(const int4*)(wb2 + 24), w2h = *(const int4*)(wb2 + 28);
  int4 w3a = *(const int4*)(wb3 + 0),  w3b = *(const int4*)(wb3 + 4);
  int4 w3c = *(const int4*)(wb3 + 8),  w3d = *(const int4*)(wb3 + 12);
  int4 w3e = *(const int4*)(wb3 + 16), w3f = *(const int4*)(wb3 + 20);
  int4 w3g = *(const int4*)(wb3 + 24), w3h = *(const int4*)(wb3 + 28);

  float fr0 = fac[dir * G4 + 0 * HID + k];
  float fr1 = fac[dir * G4 + 1 * HID + k];
  float fr2 = fac[dir * G4 + 2 * HID + k];
  float fr3 = fac[dir * G4 + 3 * HID + k];

  float* hout = dir ? hb : hf;
  const float* xbase = xg + dir * G4;
  const ptrdiff_t xstep = dir ? -2048 : 2048;
  const ptrdiff_t hstep = dir ? -HID : HID;
  float c = 0.f;
  if (tid < 64) hq[0][tid] = 0;
  __syncthreads();

  const float* xp = xbase + (size_t)(dir ? T_LEN - 1 : 0) * 2048 + k;
  float* hp = hout + (size_t)(dir ? T_LEN - 1 : 0) * HID + k;
  float xv0 = xp[0], xv1 = xp[HID], xv2 = xp[2 * HID], xv3 = xp[3 * HID];
  xp += xstep;

  for (int s = 0; s < T_LEN; ++s) {
    // Pin weights: zero-instruction asm, forbids remat-by-reload.
    PINI4(w0a); PINI4(w0b); PINI4(w0c); PINI4(w0d);
    PINI4(w0e); PINI4(w0f); PINI4(w0g); PINI4(w0h);
    PINI4(w1a); PINI4(w1b); PINI4(w1c); PINI4(w1d);
    PINI4(w1e); PINI4(w1f); PINI4(w1g); PINI4(w1h);
    PINI4(w2a); PINI4(w2b); PINI4(w2c); PINI4(w2d);
    PINI4(w2e); PINI4(w2f); PINI4(w2g); PINI4(w2h);
    PINI4(w3a); PINI4(w3b); PINI4(w3c); PINI4(w3d);
    PINI4(w3e); PINI4(w3f); PINI4(w3g); PINI4(w3h);

    // prefetch next step's xg values (independent of h -> in flight during dot)
    float xn0 = 0.f, xn1 = 0.f, xn2 = 0.f, xn3 = 0.f;
    if (s + 1 < T_LEN) {
      xn0 = xp[0]; xn1 = xp[HID]; xn2 = xp[2 * HID]; xn3 = xp[3 * HID];
    }
    xp += xstep;

    const int4* hc = (const int4*)(&hq[s & 1][half * 32]);
    int4 hv0 = hc[0], hv1 = hc[1], hv2 = hc[2], hv3 = hc[3];
    int4 hv4 = hc[4], hv5 = hc[5], hv6 = hc[6], hv7 = hc[7];
    int a0 = 0, a1 = 0, a2 = 0, a3 = 0;
    D4(w0a, hv0, a0) D4(w1a, hv0, a1) D4(w2a, hv0, a2) D4(w3a, hv0, a3)
    D4(w0b, hv1, a0) D4(w1b, hv1, a1) D4(w2b, hv1, a2) D4(w3b, hv1, a3)
    D4(w0c, hv2, a0) D4(w1c, hv2, a1) D4(w2c, hv2, a2) D4(w3c, hv2, a3)
    D4(w0d, hv3, a0) D4(w1d, hv3, a1) D4(w2d, hv3, a2) D4(w3d, hv3, a3)
    D4(w0e, hv4, a0) D4(w1e, hv4, a1) D4(w2e, hv4, a2) D4(w3e, hv4, a3)
    D4(w0f, hv5, a0) D4(w1f, hv5, a1) D4(w2f, hv5, a2) D4(w3f, hv5, a3)
    D4(w0g, hv6, a0) D4(w1g, hv6, a1) D4(w2g, hv6, a2) D4(w3g, hv6, a3)
    D4(w0h, hv7, a0) D4(w1h, hv7, a1) D4(w2h, hv7, a2) D4(w3h, hv7, a3)
    // combine K-halves within the lane pair (integer adds: bit-exact)
    a0 += __shfl_xor(a0, 1, 64);
    a1 += __shfl_xor(a1, 1, 64);
    a2 += __shfl_xor(a2, 1, 64);
    a3 += __shfl_xor(a3, 1, 64);

    float pi = xv0 + fr0 * (float)a0;
    float pf = xv1 + fr1 * (float)a1;
    float pg = xv2 + fr2 * (float)a2;
    float po = xv3 + fr3 * (float)a3;
    float iv = sigm(pi), fg = sigm(pf), gv = tanh_fast(pg), ov = sigm(po);
    c = fg * c + iv * gv;
    float h = ov * tanh_fast(c);
    int qh = (int)rintf(h * 127.0f);
    if (half == 0) {
      *hp = h;
      ((char*)(&hq[(s + 1) & 1][0]))[k] = (char)qh;
    }
    hp += hstep;
    xv0 = xn0; xv1 = xn1; xv2 = xn2; xv3 = xn3;
    __syncthreads();  // next buffer published; old buffer free to overwrite
  }
}

// ---------------------------------------------------------------------------
// feats[t][k] = W_tag[k] . [hf[t]; hb[t]] + b_tag[k]; one wave per (t,k).
// ---------------------------------------------------------------------------
__global__ __launch_bounds__(256) void feats_k(const float* __restrict__ W_tag,
                                               const float* __restrict__ b_tag,
                                               const float* __restrict__ hf,
                                               const float* __restrict__ hb,
                                               float* __restrict__ feats) {
  int pair = blockIdx.x * 4 + (threadIdx.x >> 6);
  int lane = threadIdx.x & 63;
  int t = pair / NTAG;
  int k = pair % NTAG;
  float s = 0.f;
#pragma unroll
  for (int i = 0; i < 4; ++i) {
    int j = i * 64 + lane;
    s = fmaf(W_tag[k * 512 + j], hf[(size_t)t * HID + j], s);
  }
#pragma unroll
  for (int i = 4; i < 8; ++i) {
    int j = i * 64 + lane;
    s = fmaf(W_tag[k * 512 + j], hb[(size_t)t * HID + (j - 256)], s);
  }
#pragma unroll
  for (int off = 32; off > 0; off >>= 1) s += __shfl_xor(s, off, 64);
  if (lane == 0) feats[t * NTAG + k] = s + b_tag[k];
}

// ---------------------------------------------------------------------------
// Viterbi: lane k (<12) holds fv[k]; strict-> ascending scans match
// jnp.argmax first-max tie semantics. Backpointers in LDS; lane-0 backtrace.
// Output: d_out[0]=score, d_out[1..4096]=path (as f32).
// ---------------------------------------------------------------------------
__global__ __launch_bounds__(64) void viterbi_k(const float* __restrict__ feats,
                                                const float* __restrict__ trans,
                                                float* __restrict__ out) {
  __shared__ unsigned char bpL[T_LEN * NTAG];
  int k = threadIdx.x;
  bool act = k < NTAG;
  float trc[NTAG];
#pragma unroll
  for (int p = 0; p < NTAG; ++p) trc[p] = act ? trans[k * NTAG + p] : NEGV;
  float fv = (act && k == START_TAG) ? 0.f : NEGV;
  float ft = act ? feats[k] : 0.f;
  for (int t = 0; t < T_LEN; ++t) {
    float ftn = (act && t + 1 < T_LEN) ? feats[(t + 1) * NTAG + k] : 0.f;
    float v[NTAG];
#pragma unroll
    for (int p = 0; p < NTAG; ++p) v[p] = __shfl(fv, p, 64) + trc[p];
    float bv = v[0];
    int bp = 0;
#pragma unroll
    for (int p = 1; p < NTAG; ++p) {
      if (v[p] > bv) { bv = v[p]; bp = p; }
    }
    if (act) {
      fv = bv + ft;
      bpL[t * NTAG + k] = (unsigned char)bp;
    }
    ft = ftn;
  }
  float term = act ? (fv + trans[STOP_TAG * NTAG + k]) : NEGV;
  if (k == START_TAG || k == STOP_TAG) term = NEGV;
  float bs = __shfl(term, 0, 64);
  int bk = 0;
#pragma unroll
  for (int p = 1; p < NTAG; ++p) {
    float vv = __shfl(term, p, 64);
    if (vv > bs) { bs = vv; bk = p; }
  }
  if (k == 0) {
    out[0] = bs;
    int cur = bk;
    for (int t = T_LEN - 1; t >= 0; --t) {
      out[1 + t] = (float)cur;
      cur = bpL[t * NTAG + cur];
    }
  }
}

// ---------------------------------------------------------------------------
extern "C" void kernel_launch(void* const* d_in, const int* in_sizes, int n_in,
                              void* d_out, int out_size, void* d_ws,
                              size_t ws_size, hipStream_t stream) {
  const int* words0 = (const int*)d_in[0];
  const int* words1 = (const int*)d_in[1];
  const int* words2 = (const int*)d_in[2];
  const int* words3 = (const int*)d_in[3];
  const float* W_emb  = (const float*)d_in[4];
  const float* w_ih_f = (const float*)d_in[5];
  const float* w_hh_f = (const float*)d_in[6];
  const float* b_ih_f = (const float*)d_in[7];
  const float* b_hh_f = (const float*)d_in[8];
  const float* w_ih_b = (const float*)d_in[9];
  const float* w_hh_b = (const float*)d_in[10];
  const float* b_ih_b = (const float*)d_in[11];
  const float* b_hh_b = (const float*)d_in[12];
  const float* W_tag  = (const float*)d_in[13];
  const float* b_tag  = (const float*)d_in[14];
  const float* trans  = (const float*)d_in[15];

  char* ws = (char*)d_ws;
  float* xg    = (float*)(ws);               // 4096*2048 f32 = 33,554,432 B
  float* hf    = (float*)(ws + 33554432);    // 4096*256 f32  =  4,194,304 B
  float* hb    = (float*)(ws + 37748736);    // 4096*256 f32  =  4,194,304 B
  int*   qw    = (int*)  (ws + 41943040);    // 2048*64 i32   =    524,288 B
  float* fac   = (float*)(ws + 42467328);    // 2048 f32
  float* feats = (float*)(ws + 42475520);    // 4096*12 f32

  quant_whh<<<dim3(2048), dim3(64), 0, stream>>>(w_hh_f, w_hh_b, qw, fac);
  xg_gemm<<<dim3(32, 32), dim3(256), 0, stream>>>(
      words0, words1, words2, words3, W_emb, w_ih_f, w_ih_b, b_ih_f, b_hh_f,
      b_ih_b, b_hh_b, xg);
  lstm_rec<<<dim3(2), dim3(512), 0, stream>>>(xg, qw, fac, hf, hb);
  feats_k<<<dim3(12288), dim3(256), 0, stream>>>(W_tag, b_tag, hf, hb, feats);
  viterbi_k<<<dim3(1), dim3(64), 0, stream>>>(feats, trans, (float*)d_out);
}

// Round 4
// 6500.508 us; speedup vs baseline: 1.0013x; 1.0013x over previous
//
#include <hip/hip_runtime.h>
#include <math.h>

#define T_LEN 4096
#define EMB 300
#define DIN 1200
#define HID 256
#define G4 1024           // 4*HID gate rows per direction
#define NTAG 12
#define START_TAG 10
#define STOP_TAG 11
#define NEGV -10000.0f

#if defined(__has_builtin)
#  if __has_builtin(__builtin_amdgcn_sdot4)
#    define HAVE_SDOT4 1
#  endif
#endif

__device__ __forceinline__ int sdot4(int a, int b, int c) {
#ifdef HAVE_SDOT4
  return __builtin_amdgcn_sdot4(a, b, c, false);
#else
  return c + (int)(char)(a) * (int)(char)(b)
           + (int)(char)(a >> 8) * (int)(char)(b >> 8)
           + (int)(char)(a >> 16) * (int)(char)(b >> 16)
           + (a >> 24) * (b >> 24);
#endif
}

__device__ __forceinline__ float sigm(float x) { return 1.0f / (1.0f + __expf(-x)); }
__device__ __forceinline__ float tanh_fast(float x) {
  x = fminf(fmaxf(x, -15.0f), 15.0f);
  float e = __expf(2.0f * x);
  return (e - 1.0f) / (e + 1.0f);
}

// ---------------------------------------------------------------------------
// Quantize w_hh (both directions) to int8, per-row scale.
// ---------------------------------------------------------------------------
__global__ __launch_bounds__(64) void quant_whh(const float* __restrict__ w_hh_f,
                                                const float* __restrict__ w_hh_b,
                                                int* __restrict__ qw,
                                                float* __restrict__ fac) {
  int row = blockIdx.x;   // 0..2047 (fwd rows 0..1023, bwd 1024..2047)
  int tid = threadIdx.x;  // 0..63
  const float* src = (row < G4) ? (w_hh_f + (size_t)row * HID)
                                : (w_hh_b + (size_t)(row - G4) * HID);
  float4 v = *(const float4*)(src + tid * 4);
  float m = fmaxf(fmaxf(fabsf(v.x), fabsf(v.y)), fmaxf(fabsf(v.z), fabsf(v.w)));
#pragma unroll
  for (int off = 32; off > 0; off >>= 1) m = fmaxf(m, __shfl_xor(m, off, 64));
  float inv = (m > 0.f) ? 127.0f / m : 0.f;
  int q0 = (int)rintf(v.x * inv), q1 = (int)rintf(v.y * inv);
  int q2 = (int)rintf(v.z * inv), q3 = (int)rintf(v.w * inv);
  qw[(size_t)row * 64 + tid] =
      (q0 & 255) | ((q1 & 255) << 8) | ((q2 & 255) << 16) | ((q3 & 255) << 24);
  if (tid == 0) fac[row] = m / (127.0f * 127.0f);
}

// ---------------------------------------------------------------------------
// xg[t][j] = emb_row(t) . w_ih[j] + b_ih[j] + b_hh[j];  j<1024 fwd, else bwd.
// ---------------------------------------------------------------------------
__global__ __launch_bounds__(256) void xg_gemm(
    const int* __restrict__ words0, const int* __restrict__ words1,
    const int* __restrict__ words2, const int* __restrict__ words3,
    const float* __restrict__ W_emb,
    const float* __restrict__ w_ih_f, const float* __restrict__ w_ih_b,
    const float* __restrict__ b_ih_f, const float* __restrict__ b_hh_f,
    const float* __restrict__ b_ih_b, const float* __restrict__ b_hh_b,
    float* __restrict__ xg) {
  __shared__ __align__(16) float As[16][132];
  __shared__ __align__(16) float Bs[16][68];
  __shared__ int w4[128][4];
  int tid = threadIdx.x;
  int t0 = blockIdx.x * 128;
  int n0 = blockIdx.y * 64;
  if (tid < 128) {
    int t = t0 + tid;
    w4[tid][0] = words0[t]; w4[tid][1] = words1[t];
    w4[tid][2] = words2[t]; w4[tid][3] = words3[t];
  }
  int kq = tid & 3;
  int r  = tid >> 2;
  const float* Bp = (n0 < G4) ? (w_ih_f + (size_t)(n0 + r) * DIN)
                              : (w_ih_b + (size_t)(n0 + r - G4) * DIN);
  float acc[8][4];
#pragma unroll
  for (int m = 0; m < 8; ++m)
#pragma unroll
    for (int n = 0; n < 4; ++n) acc[m][n] = 0.f;
  __syncthreads();

  for (int it = 0; it < 75; ++it) {
    int kk = it * 16 + kq * 4;
    int seg = (kk >= 900) ? 3 : (kk >= 600) ? 2 : (kk >= 300) ? 1 : 0;
    int col = kk - seg * 300;
    int wid0 = w4[r][seg];
    int wid1 = w4[r + 64][seg];
    float4 a0 = *(const float4*)(W_emb + (size_t)wid0 * EMB + col);
    float4 a1 = *(const float4*)(W_emb + (size_t)wid1 * EMB + col);
    float4 b  = *(const float4*)(Bp + kk);
    As[kq * 4 + 0][r] = a0.x; As[kq * 4 + 1][r] = a0.y;
    As[kq * 4 + 2][r] = a0.z; As[kq * 4 + 3][r] = a0.w;
    As[kq * 4 + 0][r + 64] = a1.x; As[kq * 4 + 1][r + 64] = a1.y;
    As[kq * 4 + 2][r + 64] = a1.z; As[kq * 4 + 3][r + 64] = a1.w;
    Bs[kq * 4 + 0][r] = b.x; Bs[kq * 4 + 1][r] = b.y;
    Bs[kq * 4 + 2][r] = b.z; Bs[kq * 4 + 3][r] = b.w;
    __syncthreads();
    int ii = (tid & 15) * 8;
    int jj = (tid >> 4) * 4;
#pragma unroll
    for (int k2 = 0; k2 < 16; ++k2) {
      float4 av0 = *(const float4*)&As[k2][ii];
      float4 av1 = *(const float4*)&As[k2][ii + 4];
      float4 bv  = *(const float4*)&Bs[k2][jj];
      float a[8] = {av0.x, av0.y, av0.z, av0.w, av1.x, av1.y, av1.z, av1.w};
      float bb[4] = {bv.x, bv.y, bv.z, bv.w};
#pragma unroll
      for (int m = 0; m < 8; ++m)
#pragma unroll
        for (int n = 0; n < 4; ++n) acc[m][n] = fmaf(a[m], bb[n], acc[m][n]);
    }
    __syncthreads();
  }
  int ii = (tid & 15) * 8;
  int jj = (tid >> 4) * 4;
  float bias[4];
#pragma unroll
  for (int n = 0; n < 4; ++n) {
    int jg = n0 + jj + n;
    bias[n] = (jg < G4) ? (b_ih_f[jg] + b_hh_f[jg])
                        : (b_ih_b[jg - G4] + b_hh_b[jg - G4]);
  }
#pragma unroll
  for (int m = 0; m < 8; ++m) {
    int row = t0 + ii + m;
    float4 st = make_float4(acc[m][0] + bias[0], acc[m][1] + bias[1],
                            acc[m][2] + bias[2], acc[m][3] + bias[3]);
    *(float4*)(xg + (size_t)row * 2048 + n0 + jj) = st;
  }
}

// ---------------------------------------------------------------------------
// LSTM recurrence v4. Identical to v3 EXCEPT __launch_bounds__(512, 1).
// Round-3 post-mortem: with (512,2) the effective VGPR cap was 128 (hipcc
// applies CUDA-style "min blocks/CU" to the 2nd arg: 2 blocks x 8 waves =
// 4 waves/SIMD -> 512/4 = 128 regs). The asm pins then forced a SCRATCH
// spill of the ~67 words over budget (VGPR_Count dropped to 80, dur rose).
// With min=1: 1 block/CU -> 2 waves/SIMD -> cap 256 >= the ~195 live words,
// so the pinned weights can finally be register-resident.
// Bit-identical numerics vs rounds 1-3.
// ---------------------------------------------------------------------------
#define D4(W, H, A)                                         \
  A = sdot4(W.x, H.x, A); A = sdot4(W.y, H.y, A);           \
  A = sdot4(W.z, H.z, A); A = sdot4(W.w, H.w, A);

#define PINI4(v) asm volatile("" : "+v"(v.x), "+v"(v.y), "+v"(v.z), "+v"(v.w))

__global__ __launch_bounds__(512, 1) void lstm_rec(
    const float* __restrict__ xg, const int* __restrict__ qw,
    const float* __restrict__ fac, float* __restrict__ hf,
    float* __restrict__ hb) {
  int dir = blockIdx.x;
  int tid = threadIdx.x;
  int k = tid >> 1;        // hidden unit 0..255
  int half = tid & 1;      // K-half 0..1 (partner lane is tid^1, same wave)
  __shared__ __align__(16) int hq[2][64];   // packed int8 h, double-buffered

  const int* wb0 = qw + (size_t)(dir * G4 + 0 * HID + k) * 64 + half * 32;
  const int* wb1 = qw + (size_t)(dir * G4 + 1 * HID + k) * 64 + half * 32;
  const int* wb2 = qw + (size_t)(dir * G4 + 2 * HID + k) * 64 + half * 32;
  const int* wb3 = qw + (size_t)(dir * G4 + 3 * HID + k) * 64 + half * 32;
  int4 w0a = *(const int4*)(wb0 + 0),  w0b = *(const int4*)(wb0 + 4);
  int4 w0c = *(const int4*)(wb0 + 8),  w0d = *(const int4*)(wb0 + 12);
  int4 w0e = *(const int4*)(wb0 + 16), w0f = *(const int4*)(wb0 + 20);
  int4 w0g = *(const int4*)(wb0 + 24), w0h = *(const int4*)(wb0 + 28);
  int4 w1a = *(const int4*)(wb1 + 0),  w1b = *(const int4*)(wb1 + 4);
  int4 w1c = *(const int4*)(wb1 + 8),  w1d = *(const int4*)(wb1 + 12);
  int4 w1e = *(const int4*)(wb1 + 16), w1f = *(const int4*)(wb1 + 20);
  int4 w1g = *(const int4*)(wb1 + 24), w1h = *(const int4*)(wb1 + 28);
  int4 w2a = *(const int4*)(wb2 + 0),  w2b = *(const int4*)(wb2 + 4);
  int4 w2c = *(const int4*)(wb2 + 8),  w2d = *(const int4*)(wb2 + 12);
  int4 w2e = *(const int4*)(wb2 + 16), w2f = *(const int4*)(wb2 + 20);
  int4 w2g = *(const int4*)(wb2 + 24), w2h = *(const int4*)(wb2 + 28);
  int4 w3a = *(const int4*)(wb3 + 0),  w3b = *(const int4*)(wb3 + 4);
  int4 w3c = *(const int4*)(wb3 + 8),  w3d = *(const int4*)(wb3 + 12);
  int4 w3e = *(const int4*)(wb3 + 16), w3f = *(const int4*)(wb3 + 20);
  int4 w3g = *(const int4*)(wb3 + 24), w3h = *(const int4*)(wb3 + 28);

  float fr0 = fac[dir * G4 + 0 * HID + k];
  float fr1 = fac[dir * G4 + 1 * HID + k];
  float fr2 = fac[dir * G4 + 2 * HID + k];
  float fr3 = fac[dir * G4 + 3 * HID + k];

  float* hout = dir ? hb : hf;
  const float* xbase = xg + dir * G4;
  const ptrdiff_t xstep = dir ? -2048 : 2048;
  const ptrdiff_t hstep = dir ? -HID : HID;
  float c = 0.f;
  if (tid < 64) hq[0][tid] = 0;
  __syncthreads();

  const float* xp = xbase + (size_t)(dir ? T_LEN - 1 : 0) * 2048 + k;
  float* hp = hout + (size_t)(dir ? T_LEN - 1 : 0) * HID + k;
  float xv0 = xp[0], xv1 = xp[HID], xv2 = xp[2 * HID], xv3 = xp[3 * HID];
  xp += xstep;

  for (int s = 0; s < T_LEN; ++s) {
    // Pin weights: zero-instruction asm, forbids remat-by-reload.
    PINI4(w0a); PINI4(w0b); PINI4(w0c); PINI4(w0d);
    PINI4(w0e); PINI4(w0f); PINI4(w0g); PINI4(w0h);
    PINI4(w1a); PINI4(w1b); PINI4(w1c); PINI4(w1d);
    PINI4(w1e); PINI4(w1f); PINI4(w1g); PINI4(w1h);
    PINI4(w2a); PINI4(w2b); PINI4(w2c); PINI4(w2d);
    PINI4(w2e); PINI4(w2f); PINI4(w2g); PINI4(w2h);
    PINI4(w3a); PINI4(w3b); PINI4(w3c); PINI4(w3d);
    PINI4(w3e); PINI4(w3f); PINI4(w3g); PINI4(w3h);

    // prefetch next step's xg values (independent of h -> in flight during dot)
    float xn0 = 0.f, xn1 = 0.f, xn2 = 0.f, xn3 = 0.f;
    if (s + 1 < T_LEN) {
      xn0 = xp[0]; xn1 = xp[HID]; xn2 = xp[2 * HID]; xn3 = xp[3 * HID];
    }
    xp += xstep;

    const int4* hc = (const int4*)(&hq[s & 1][half * 32]);
    int4 hv0 = hc[0], hv1 = hc[1], hv2 = hc[2], hv3 = hc[3];
    int4 hv4 = hc[4], hv5 = hc[5], hv6 = hc[6], hv7 = hc[7];
    int a0 = 0, a1 = 0, a2 = 0, a3 = 0;
    D4(w0a, hv0, a0) D4(w1a, hv0, a1) D4(w2a, hv0, a2) D4(w3a, hv0, a3)
    D4(w0b, hv1, a0) D4(w1b, hv1, a1) D4(w2b, hv1, a2) D4(w3b, hv1, a3)
    D4(w0c, hv2, a0) D4(w1c, hv2, a1) D4(w2c, hv2, a2) D4(w3c, hv2, a3)
    D4(w0d, hv3, a0) D4(w1d, hv3, a1) D4(w2d, hv3, a2) D4(w3d, hv3, a3)
    D4(w0e, hv4, a0) D4(w1e, hv4, a1) D4(w2e, hv4, a2) D4(w3e, hv4, a3)
    D4(w0f, hv5, a0) D4(w1f, hv5, a1) D4(w2f, hv5, a2) D4(w3f, hv5, a3)
    D4(w0g, hv6, a0) D4(w1g, hv6, a1) D4(w2g, hv6, a2) D4(w3g, hv6, a3)
    D4(w0h, hv7, a0) D4(w1h, hv7, a1) D4(w2h, hv7, a2) D4(w3h, hv7, a3)
    // combine K-halves within the lane pair (integer adds: bit-exact)
    a0 += __shfl_xor(a0, 1, 64);
    a1 += __shfl_xor(a1, 1, 64);
    a2 += __shfl_xor(a2, 1, 64);
    a3 += __shfl_xor(a3, 1, 64);

    float pi = xv0 + fr0 * (float)a0;
    float pf = xv1 + fr1 * (float)a1;
    float pg = xv2 + fr2 * (float)a2;
    float po = xv3 + fr3 * (float)a3;
    float iv = sigm(pi), fg = sigm(pf), gv = tanh_fast(pg), ov = sigm(po);
    c = fg * c + iv * gv;
    float h = ov * tanh_fast(c);
    int qh = (int)rintf(h * 127.0f);
    if (half == 0) {
      *hp = h;
      ((char*)(&hq[(s + 1) & 1][0]))[k] = (char)qh;
    }
    hp += hstep;
    xv0 = xn0; xv1 = xn1; xv2 = xn2; xv3 = xn3;
    __syncthreads();  // next buffer published; old buffer free to overwrite
  }
}

// ---------------------------------------------------------------------------
// feats[t][k] = W_tag[k] . [hf[t]; hb[t]] + b_tag[k]; one wave per (t,k).
// ---------------------------------------------------------------------------
__global__ __launch_bounds__(256) void feats_k(const float* __restrict__ W_tag,
                                               const float* __restrict__ b_tag,
                                               const float* __restrict__ hf,
                                               const float* __restrict__ hb,
                                               float* __restrict__ feats) {
  int pair = blockIdx.x * 4 + (threadIdx.x >> 6);
  int lane = threadIdx.x & 63;
  int t = pair / NTAG;
  int k = pair % NTAG;
  float s = 0.f;
#pragma unroll
  for (int i = 0; i < 4; ++i) {
    int j = i * 64 + lane;
    s = fmaf(W_tag[k * 512 + j], hf[(size_t)t * HID + j], s);
  }
#pragma unroll
  for (int i = 4; i < 8; ++i) {
    int j = i * 64 + lane;
    s = fmaf(W_tag[k * 512 + j], hb[(size_t)t * HID + (j - 256)], s);
  }
#pragma unroll
  for (int off = 32; off > 0; off >>= 1) s += __shfl_xor(s, off, 64);
  if (lane == 0) feats[t * NTAG + k] = s + b_tag[k];
}

// ---------------------------------------------------------------------------
// Viterbi: lane k (<12) holds fv[k]; strict-> ascending scans match
// jnp.argmax first-max tie semantics. Backpointers in LDS; lane-0 backtrace.
// Output: d_out[0]=score, d_out[1..4096]=path (as f32).
// ---------------------------------------------------------------------------
__global__ __launch_bounds__(64) void viterbi_k(const float* __restrict__ feats,
                                                const float* __restrict__ trans,
                                                float* __restrict__ out) {
  __shared__ unsigned char bpL[T_LEN * NTAG];
  int k = threadIdx.x;
  bool act = k < NTAG;
  float trc[NTAG];
#pragma unroll
  for (int p = 0; p < NTAG; ++p) trc[p] = act ? trans[k * NTAG + p] : NEGV;
  float fv = (act && k == START_TAG) ? 0.f : NEGV;
  float ft = act ? feats[k] : 0.f;
  for (int t = 0; t < T_LEN; ++t) {
    float ftn = (act && t + 1 < T_LEN) ? feats[(t + 1) * NTAG + k] : 0.f;
    float v[NTAG];
#pragma unroll
    for (int p = 0; p < NTAG; ++p) v[p] = __shfl(fv, p, 64) + trc[p];
    float bv = v[0];
    int bp = 0;
#pragma unroll
    for (int p = 1; p < NTAG; ++p) {
      if (v[p] > bv) { bv = v[p]; bp = p; }
    }
    if (act) {
      fv = bv + ft;
      bpL[t * NTAG + k] = (unsigned char)bp;
    }
    ft = ftn;
  }
  float term = act ? (fv + trans[STOP_TAG * NTAG + k]) : NEGV;
  if (k == START_TAG || k == STOP_TAG) term = NEGV;
  float bs = __shfl(term, 0, 64);
  int bk = 0;
#pragma unroll
  for (int p = 1; p < NTAG; ++p) {
    float vv = __shfl(term, p, 64);
    if (vv > bs) { bs = vv; bk = p; }
  }
  if (k == 0) {
    out[0] = bs;
    int cur = bk;
    for (int t = T_LEN - 1; t >= 0; --t) {
      out[1 + t] = (float)cur;
      cur = bpL[t * NTAG + cur];
    }
  }
}

// ---------------------------------------------------------------------------
extern "C" void kernel_launch(void* const* d_in, const int* in_sizes, int n_in,
                              void* d_out, int out_size, void* d_ws,
                              size_t ws_size, hipStream_t stream) {
  const int* words0 = (const int*)d_in[0];
  const int* words1 = (const int*)d_in[1];
  const int* words2 = (const int*)d_in[2];
  const int* words3 = (const int*)d_in[3];
  const float* W_emb  = (const float*)d_in[4];
  const float* w_ih_f = (const float*)d_in[5];
  const float* w_hh_f = (const float*)d_in[6];
  const float* b_ih_f = (const float*)d_in[7];
  const float* b_hh_f = (const float*)d_in[8];
  const float* w_ih_b = (const float*)d_in[9];
  const float* w_hh_b = (const float*)d_in[10];
  const float* b_ih_b = (const float*)d_in[11];
  const float* b_hh_b = (const float*)d_in[12];
  const float* W_tag  = (const float*)d_in[13];
  const float* b_tag  = (const float*)d_in[14];
  const float* trans  = (const float*)d_in[15];

  char* ws = (char*)d_ws;
  float* xg    = (float*)(ws);               // 4096*2048 f32 = 33,554,432 B
  float* hf    = (float*)(ws + 33554432);    // 4096*256 f32  =  4,194,304 B
  float* hb    = (float*)(ws + 37748736);    // 4096*256 f32  =  4,194,304 B
  int*   qw    = (int*)  (ws + 41943040);    // 2048*64 i32   =    524,288 B
  float* fac   = (float*)(ws + 42467328);    // 2048 f32
  float* feats = (float*)(ws + 42475520);    // 4096*12 f32

  quant_whh<<<dim3(2048), dim3(64), 0, stream>>>(w_hh_f, w_hh_b, qw, fac);
  xg_gemm<<<dim3(32, 32), dim3(256), 0, stream>>>(
      words0, words1, words2, words3, W_emb, w_ih_f, w_ih_b, b_ih_f, b_hh_f,
      b_ih_b, b_hh_b, xg);
  lstm_rec<<<dim3(2), dim3(512), 0, stream>>>(xg, qw, fac, hf, hb);
  feats_k<<<dim3(12288), dim3(256), 0, stream>>>(W_tag, b_tag, hf, hb, feats);
  viterbi_k<<<dim3(1), dim3(64), 0, stream>>>(feats, trans, (float*)d_out);
}

// Round 5
// 5740.549 us; speedup vs baseline: 1.1338x; 1.1324x over previous
//
#include <hip/hip_runtime.h>
#include <math.h>

#define T_LEN 4096
#define EMB 300
#define DIN 1200
#define HID 256
#define G4 1024           // 4*HID gate rows per direction
#define NTAG 12
#define START_TAG 10
#define STOP_TAG 11
#define NEGV -10000.0f

#if defined(__has_builtin)
#  if __has_builtin(__builtin_amdgcn_sdot4)
#    define HAVE_SDOT4 1
#  endif
#endif

__device__ __forceinline__ int sdot4(int a, int b, int c) {
#ifdef HAVE_SDOT4
  return __builtin_amdgcn_sdot4(a, b, c, false);
#else
  return c + (int)(char)(a) * (int)(char)(b)
           + (int)(char)(a >> 8) * (int)(char)(b >> 8)
           + (int)(char)(a >> 16) * (int)(char)(b >> 16)
           + (a >> 24) * (b >> 24);
#endif
}

__device__ __forceinline__ float sigm(float x) { return 1.0f / (1.0f + __expf(-x)); }
__device__ __forceinline__ float tanh_fast(float x) {
  x = fminf(fmaxf(x, -15.0f), 15.0f);
  float e = __expf(2.0f * x);
  return (e - 1.0f) / (e + 1.0f);
}

// ---------------------------------------------------------------------------
// Quantize w_hh (both directions) to int8, per-row scale.
// ---------------------------------------------------------------------------
__global__ __launch_bounds__(64) void quant_whh(const float* __restrict__ w_hh_f,
                                                const float* __restrict__ w_hh_b,
                                                int* __restrict__ qw,
                                                float* __restrict__ fac) {
  int row = blockIdx.x;   // 0..2047 (fwd rows 0..1023, bwd 1024..2047)
  int tid = threadIdx.x;  // 0..63
  const float* src = (row < G4) ? (w_hh_f + (size_t)row * HID)
                                : (w_hh_b + (size_t)(row - G4) * HID);
  float4 v = *(const float4*)(src + tid * 4);
  float m = fmaxf(fmaxf(fabsf(v.x), fabsf(v.y)), fmaxf(fabsf(v.z), fabsf(v.w)));
#pragma unroll
  for (int off = 32; off > 0; off >>= 1) m = fmaxf(m, __shfl_xor(m, off, 64));
  float inv = (m > 0.f) ? 127.0f / m : 0.f;
  int q0 = (int)rintf(v.x * inv), q1 = (int)rintf(v.y * inv);
  int q2 = (int)rintf(v.z * inv), q3 = (int)rintf(v.w * inv);
  qw[(size_t)row * 64 + tid] =
      (q0 & 255) | ((q1 & 255) << 8) | ((q2 & 255) << 16) | ((q3 & 255) << 24);
  if (tid == 0) fac[row] = m / (127.0f * 127.0f);
}

// ---------------------------------------------------------------------------
// xg[t][j] = emb_row(t) . w_ih[j] + b_ih[j] + b_hh[j];  j<1024 fwd, else bwd.
// ---------------------------------------------------------------------------
__global__ __launch_bounds__(256) void xg_gemm(
    const int* __restrict__ words0, const int* __restrict__ words1,
    const int* __restrict__ words2, const int* __restrict__ words3,
    const float* __restrict__ W_emb,
    const float* __restrict__ w_ih_f, const float* __restrict__ w_ih_b,
    const float* __restrict__ b_ih_f, const float* __restrict__ b_hh_f,
    const float* __restrict__ b_ih_b, const float* __restrict__ b_hh_b,
    float* __restrict__ xg) {
  __shared__ __align__(16) float As[16][132];
  __shared__ __align__(16) float Bs[16][68];
  __shared__ int w4[128][4];
  int tid = threadIdx.x;
  int t0 = blockIdx.x * 128;
  int n0 = blockIdx.y * 64;
  if (tid < 128) {
    int t = t0 + tid;
    w4[tid][0] = words0[t]; w4[tid][1] = words1[t];
    w4[tid][2] = words2[t]; w4[tid][3] = words3[t];
  }
  int kq = tid & 3;
  int r  = tid >> 2;
  const float* Bp = (n0 < G4) ? (w_ih_f + (size_t)(n0 + r) * DIN)
                              : (w_ih_b + (size_t)(n0 + r - G4) * DIN);
  float acc[8][4];
#pragma unroll
  for (int m = 0; m < 8; ++m)
#pragma unroll
    for (int n = 0; n < 4; ++n) acc[m][n] = 0.f;
  __syncthreads();

  for (int it = 0; it < 75; ++it) {
    int kk = it * 16 + kq * 4;
    int seg = (kk >= 900) ? 3 : (kk >= 600) ? 2 : (kk >= 300) ? 1 : 0;
    int col = kk - seg * 300;
    int wid0 = w4[r][seg];
    int wid1 = w4[r + 64][seg];
    float4 a0 = *(const float4*)(W_emb + (size_t)wid0 * EMB + col);
    float4 a1 = *(const float4*)(W_emb + (size_t)wid1 * EMB + col);
    float4 b  = *(const float4*)(Bp + kk);
    As[kq * 4 + 0][r] = a0.x; As[kq * 4 + 1][r] = a0.y;
    As[kq * 4 + 2][r] = a0.z; As[kq * 4 + 3][r] = a0.w;
    As[kq * 4 + 0][r + 64] = a1.x; As[kq * 4 + 1][r + 64] = a1.y;
    As[kq * 4 + 2][r + 64] = a1.z; As[kq * 4 + 3][r + 64] = a1.w;
    Bs[kq * 4 + 0][r] = b.x; Bs[kq * 4 + 1][r] = b.y;
    Bs[kq * 4 + 2][r] = b.z; Bs[kq * 4 + 3][r] = b.w;
    __syncthreads();
    int ii = (tid & 15) * 8;
    int jj = (tid >> 4) * 4;
#pragma unroll
    for (int k2 = 0; k2 < 16; ++k2) {
      float4 av0 = *(const float4*)&As[k2][ii];
      float4 av1 = *(const float4*)&As[k2][ii + 4];
      float4 bv  = *(const float4*)&Bs[k2][jj];
      float a[8] = {av0.x, av0.y, av0.z, av0.w, av1.x, av1.y, av1.z, av1.w};
      float bb[4] = {bv.x, bv.y, bv.z, bv.w};
#pragma unroll
      for (int m = 0; m < 8; ++m)
#pragma unroll
        for (int n = 0; n < 4; ++n) acc[m][n] = fmaf(a[m], bb[n], acc[m][n]);
    }
    __syncthreads();
  }
  int ii = (tid & 15) * 8;
  int jj = (tid >> 4) * 4;
  float bias[4];
#pragma unroll
  for (int n = 0; n < 4; ++n) {
    int jg = n0 + jj + n;
    bias[n] = (jg < G4) ? (b_ih_f[jg] + b_hh_f[jg])
                        : (b_ih_b[jg - G4] + b_hh_b[jg - G4]);
  }
#pragma unroll
  for (int m = 0; m < 8; ++m) {
    int row = t0 + ii + m;
    float4 st = make_float4(acc[m][0] + bias[0], acc[m][1] + bias[1],
                            acc[m][2] + bias[2], acc[m][3] + bias[3]);
    *(float4*)(xg + (size_t)row * 2048 + n0 + jj) = st;
  }
}

// ---------------------------------------------------------------------------
// LSTM recurrence v5: ONE THREAD PER GATE ROW.
// Rounds 2-4 post-mortem: with 128 weight words/thread the allocator always
// either re-loaded per step (r2, VGPR=88) or scratch-spilled the pinned
// values (r3/r4, VGPR=80) -- it will not hold 128. This version needs only
// 64 weight VGPRs/thread: 1024 threads/block (16 waves, 4/SIMD), thread tid
// owns gate row tid with the FULL K=256 (64 int32 of int8 weights, 16 named
// int4s). No shuffle reduction. Per step:
//   phase 1 (all): 64 sdot4 over broadcast h (4 accs, int-assoc exact),
//                  pre[tid] = x + fac*dot -> LDS; barrier A.
//   phase 2 (tid<256, waves 0-3): gate math, c/h update, write h + quantized
//                  int8 h into the OTHER hq buffer; barrier B.
// Bit-identical trajectory vs rounds 1-4 (integer reassociation only).
// ---------------------------------------------------------------------------
#define D4(W, H, A)                                         \
  A = sdot4(W.x, H.x, A); A = sdot4(W.y, H.y, A);           \
  A = sdot4(W.z, H.z, A); A = sdot4(W.w, H.w, A);

#define PINI4(v) asm volatile("" : "+v"(v.x), "+v"(v.y), "+v"(v.z), "+v"(v.w))

__global__ __launch_bounds__(1024) void lstm_rec(
    const float* __restrict__ xg, const int* __restrict__ qw,
    const float* __restrict__ fac, float* __restrict__ hf,
    float* __restrict__ hb) {
  int dir = blockIdx.x;
  int tid = threadIdx.x;                    // gate row within direction
  __shared__ __align__(16) int hq[2][64];   // packed int8 h, double-buffered
  __shared__ float pre[G4];                 // preactivations

  const int* wp = qw + (size_t)(dir * G4 + tid) * 64;
  int4 w0 = ((const int4*)wp)[0],  w1 = ((const int4*)wp)[1];
  int4 w2 = ((const int4*)wp)[2],  w3 = ((const int4*)wp)[3];
  int4 w4_ = ((const int4*)wp)[4], w5 = ((const int4*)wp)[5];
  int4 w6 = ((const int4*)wp)[6],  w7 = ((const int4*)wp)[7];
  int4 w8 = ((const int4*)wp)[8],  w9 = ((const int4*)wp)[9];
  int4 wa = ((const int4*)wp)[10], wb = ((const int4*)wp)[11];
  int4 wc = ((const int4*)wp)[12], wd = ((const int4*)wp)[13];
  int4 we = ((const int4*)wp)[14], wf = ((const int4*)wp)[15];
  float fr = fac[dir * G4 + tid];

  int k = tid & (HID - 1);                  // hidden unit (phase-2 identity)
  float* hout = dir ? hb : hf;
  const ptrdiff_t xstep = dir ? -2048 : 2048;
  const ptrdiff_t hstep = dir ? -HID : HID;
  const float* xp = xg + (size_t)(dir ? T_LEN - 1 : 0) * 2048 + dir * G4 + tid;
  float* hp = hout + (size_t)(dir ? T_LEN - 1 : 0) * HID + k;  // in-bounds all
  float c = 0.f;
  if (tid < 64) hq[0][tid] = 0;
  __syncthreads();

  float xv = *xp;

  for (int s = 0; s < T_LEN; ++s) {
    // Pin weights (zero-cost): forbid remat-by-reload; 64 words fits budget.
    PINI4(w0); PINI4(w1); PINI4(w2); PINI4(w3);
    PINI4(w4_); PINI4(w5); PINI4(w6); PINI4(w7);
    PINI4(w8); PINI4(w9); PINI4(wa); PINI4(wb);
    PINI4(wc); PINI4(wd); PINI4(we); PINI4(wf);

    // prefetch next step's x (coalesced, independent of h)
    float xn = 0.f;
    if (s + 1 < T_LEN) { xp += xstep; xn = *xp; }

    // full-K dot over broadcast h; 4 accumulators (int-assoc, bit-exact)
    const int4* hc = (const int4*)(&hq[s & 1][0]);
    int a0 = 0, a1 = 0, a2 = 0, a3 = 0;
    {
      int4 h0 = hc[0], h1 = hc[1], h2 = hc[2], h3 = hc[3];
      D4(w0, h0, a0) D4(w1, h1, a1) D4(w2, h2, a2) D4(w3, h3, a3)
      h0 = hc[4]; h1 = hc[5]; h2 = hc[6]; h3 = hc[7];
      D4(w4_, h0, a0) D4(w5, h1, a1) D4(w6, h2, a2) D4(w7, h3, a3)
      h0 = hc[8]; h1 = hc[9]; h2 = hc[10]; h3 = hc[11];
      D4(w8, h0, a0) D4(w9, h1, a1) D4(wa, h2, a2) D4(wb, h3, a3)
      h0 = hc[12]; h1 = hc[13]; h2 = hc[14]; h3 = hc[15];
      D4(wc, h0, a0) D4(wd, h1, a1) D4(we, h2, a2) D4(wf, h3, a3)
    }
    int a = (a0 + a1) + (a2 + a3);
    pre[tid] = xv + fr * (float)a;
    __syncthreads();  // A: all preactivations visible

    if (tid < HID) {  // waves 0-3 (one per SIMD) do the pointwise update
      float pi = pre[tid];
      float pf = pre[HID + tid];
      float pg = pre[2 * HID + tid];
      float po = pre[3 * HID + tid];
      float iv = sigm(pi), fg = sigm(pf), gv = tanh_fast(pg), ov = sigm(po);
      c = fg * c + iv * gv;
      float h = ov * tanh_fast(c);
      *hp = h;
      ((char*)(&hq[(s + 1) & 1][0]))[tid] = (char)(int)rintf(h * 127.0f);
    }
    hp += hstep;
    xv = xn;
    __syncthreads();  // B: next h buffer published; pre[] free to overwrite
  }
}

// ---------------------------------------------------------------------------
// feats[t][k] = W_tag[k] . [hf[t]; hb[t]] + b_tag[k]; one wave per (t,k).
// ---------------------------------------------------------------------------
__global__ __launch_bounds__(256) void feats_k(const float* __restrict__ W_tag,
                                               const float* __restrict__ b_tag,
                                               const float* __restrict__ hf,
                                               const float* __restrict__ hb,
                                               float* __restrict__ feats) {
  int pair = blockIdx.x * 4 + (threadIdx.x >> 6);
  int lane = threadIdx.x & 63;
  int t = pair / NTAG;
  int k = pair % NTAG;
  float s = 0.f;
#pragma unroll
  for (int i = 0; i < 4; ++i) {
    int j = i * 64 + lane;
    s = fmaf(W_tag[k * 512 + j], hf[(size_t)t * HID + j], s);
  }
#pragma unroll
  for (int i = 4; i < 8; ++i) {
    int j = i * 64 + lane;
    s = fmaf(W_tag[k * 512 + j], hb[(size_t)t * HID + (j - 256)], s);
  }
#pragma unroll
  for (int off = 32; off > 0; off >>= 1) s += __shfl_xor(s, off, 64);
  if (lane == 0) feats[t * NTAG + k] = s + b_tag[k];
}

// ---------------------------------------------------------------------------
// Viterbi: lane k (<12) holds fv[k]; strict-> ascending scans match
// jnp.argmax first-max tie semantics. Backpointers in LDS; lane-0 backtrace.
// Output: d_out[0]=score, d_out[1..4096]=path (as f32).
// ---------------------------------------------------------------------------
__global__ __launch_bounds__(64) void viterbi_k(const float* __restrict__ feats,
                                                const float* __restrict__ trans,
                                                float* __restrict__ out) {
  __shared__ unsigned char bpL[T_LEN * NTAG];
  int k = threadIdx.x;
  bool act = k < NTAG;
  float trc[NTAG];
#pragma unroll
  for (int p = 0; p < NTAG; ++p) trc[p] = act ? trans[k * NTAG + p] : NEGV;
  float fv = (act && k == START_TAG) ? 0.f : NEGV;
  float ft = act ? feats[k] : 0.f;
  for (int t = 0; t < T_LEN; ++t) {
    float ftn = (act && t + 1 < T_LEN) ? feats[(t + 1) * NTAG + k] : 0.f;
    float v[NTAG];
#pragma unroll
    for (int p = 0; p < NTAG; ++p) v[p] = __shfl(fv, p, 64) + trc[p];
    float bv = v[0];
    int bp = 0;
#pragma unroll
    for (int p = 1; p < NTAG; ++p) {
      if (v[p] > bv) { bv = v[p]; bp = p; }
    }
    if (act) {
      fv = bv + ft;
      bpL[t * NTAG + k] = (unsigned char)bp;
    }
    ft = ftn;
  }
  float term = act ? (fv + trans[STOP_TAG * NTAG + k]) : NEGV;
  if (k == START_TAG || k == STOP_TAG) term = NEGV;
  float bs = __shfl(term, 0, 64);
  int bk = 0;
#pragma unroll
  for (int p = 1; p < NTAG; ++p) {
    float vv = __shfl(term, p, 64);
    if (vv > bs) { bs = vv; bk = p; }
  }
  if (k == 0) {
    out[0] = bs;
    int cur = bk;
    for (int t = T_LEN - 1; t >= 0; --t) {
      out[1 + t] = (float)cur;
      cur = bpL[t * NTAG + cur];
    }
  }
}

// ---------------------------------------------------------------------------
extern "C" void kernel_launch(void* const* d_in, const int* in_sizes, int n_in,
                              void* d_out, int out_size, void* d_ws,
                              size_t ws_size, hipStream_t stream) {
  const int* words0 = (const int*)d_in[0];
  const int* words1 = (const int*)d_in[1];
  const int* words2 = (const int*)d_in[2];
  const int* words3 = (const int*)d_in[3];
  const float* W_emb  = (const float*)d_in[4];
  const float* w_ih_f = (const float*)d_in[5];
  const float* w_hh_f = (const float*)d_in[6];
  const float* b_ih_f = (const float*)d_in[7];
  const float* b_hh_f = (const float*)d_in[8];
  const float* w_ih_b = (const float*)d_in[9];
  const float* w_hh_b = (const float*)d_in[10];
  const float* b_ih_b = (const float*)d_in[11];
  const float* b_hh_b = (const float*)d_in[12];
  const float* W_tag  = (const float*)d_in[13];
  const float* b_tag  = (const float*)d_in[14];
  const float* trans  = (const float*)d_in[15];

  char* ws = (char*)d_ws;
  float* xg    = (float*)(ws);               // 4096*2048 f32 = 33,554,432 B
  float* hf    = (float*)(ws + 33554432);    // 4096*256 f32  =  4,194,304 B
  float* hb    = (float*)(ws + 37748736);    // 4096*256 f32  =  4,194,304 B
  int*   qw    = (int*)  (ws + 41943040);    // 2048*64 i32   =    524,288 B
  float* fac   = (float*)(ws + 42467328);    // 2048 f32
  float* feats = (float*)(ws + 42475520);    // 4096*12 f32

  quant_whh<<<dim3(2048), dim3(64), 0, stream>>>(w_hh_f, w_hh_b, qw, fac);
  xg_gemm<<<dim3(32, 32), dim3(256), 0, stream>>>(
      words0, words1, words2, words3, W_emb, w_ih_f, w_ih_b, b_ih_f, b_hh_f,
      b_ih_b, b_hh_b, xg);
  lstm_rec<<<dim3(2), dim3(1024), 0, stream>>>(xg, qw, fac, hf, hb);
  feats_k<<<dim3(12288), dim3(256), 0, stream>>>(W_tag, b_tag, hf, hb, feats);
  viterbi_k<<<dim3(1), dim3(64), 0, stream>>>(feats, trans, (float*)d_out);
}

// Round 6
// 5590.298 us; speedup vs baseline: 1.1643x; 1.0269x over previous
//
#include <hip/hip_runtime.h>
#include <math.h>

#define T_LEN 4096
#define EMB 300
#define DIN 1200
#define HID 256
#define G4 1024           // 4*HID gate rows per direction
#define NTAG 12
#define START_TAG 10
#define STOP_TAG 11
#define NEGV -10000.0f

#if defined(__has_builtin)
#  if __has_builtin(__builtin_amdgcn_sdot4)
#    define HAVE_SDOT4 1
#  endif
#endif

__device__ __forceinline__ int sdot4(int a, int b, int c) {
#ifdef HAVE_SDOT4
  return __builtin_amdgcn_sdot4(a, b, c, false);
#else
  return c + (int)(char)(a) * (int)(char)(b)
           + (int)(char)(a >> 8) * (int)(char)(b >> 8)
           + (int)(char)(a >> 16) * (int)(char)(b >> 16)
           + (a >> 24) * (b >> 24);
#endif
}

__device__ __forceinline__ float sigm(float x) { return 1.0f / (1.0f + __expf(-x)); }
__device__ __forceinline__ float tanh_fast(float x) {
  x = fminf(fmaxf(x, -15.0f), 15.0f);
  float e = __expf(2.0f * x);
  return (e - 1.0f) / (e + 1.0f);
}

// ---------------------------------------------------------------------------
// Quantize w_hh (both directions) to int8, per-row scale.
// ---------------------------------------------------------------------------
__global__ __launch_bounds__(64) void quant_whh(const float* __restrict__ w_hh_f,
                                                const float* __restrict__ w_hh_b,
                                                int* __restrict__ qw,
                                                float* __restrict__ fac) {
  int row = blockIdx.x;   // 0..2047 (fwd rows 0..1023, bwd 1024..2047)
  int tid = threadIdx.x;  // 0..63
  const float* src = (row < G4) ? (w_hh_f + (size_t)row * HID)
                                : (w_hh_b + (size_t)(row - G4) * HID);
  float4 v = *(const float4*)(src + tid * 4);
  float m = fmaxf(fmaxf(fabsf(v.x), fabsf(v.y)), fmaxf(fabsf(v.z), fabsf(v.w)));
#pragma unroll
  for (int off = 32; off > 0; off >>= 1) m = fmaxf(m, __shfl_xor(m, off, 64));
  float inv = (m > 0.f) ? 127.0f / m : 0.f;
  int q0 = (int)rintf(v.x * inv), q1 = (int)rintf(v.y * inv);
  int q2 = (int)rintf(v.z * inv), q3 = (int)rintf(v.w * inv);
  qw[(size_t)row * 64 + tid] =
      (q0 & 255) | ((q1 & 255) << 8) | ((q2 & 255) << 16) | ((q3 & 255) << 24);
  if (tid == 0) fac[row] = m / (127.0f * 127.0f);
}

// ---------------------------------------------------------------------------
// xg[t][j] = emb_row(t) . w_ih[j] + b_ih[j] + b_hh[j];  j<1024 fwd, else bwd.
// ---------------------------------------------------------------------------
__global__ __launch_bounds__(256) void xg_gemm(
    const int* __restrict__ words0, const int* __restrict__ words1,
    const int* __restrict__ words2, const int* __restrict__ words3,
    const float* __restrict__ W_emb,
    const float* __restrict__ w_ih_f, const float* __restrict__ w_ih_b,
    const float* __restrict__ b_ih_f, const float* __restrict__ b_hh_f,
    const float* __restrict__ b_ih_b, const float* __restrict__ b_hh_b,
    float* __restrict__ xg) {
  __shared__ __align__(16) float As[16][132];
  __shared__ __align__(16) float Bs[16][68];
  __shared__ int w4[128][4];
  int tid = threadIdx.x;
  int t0 = blockIdx.x * 128;
  int n0 = blockIdx.y * 64;
  if (tid < 128) {
    int t = t0 + tid;
    w4[tid][0] = words0[t]; w4[tid][1] = words1[t];
    w4[tid][2] = words2[t]; w4[tid][3] = words3[t];
  }
  int kq = tid & 3;
  int r  = tid >> 2;
  const float* Bp = (n0 < G4) ? (w_ih_f + (size_t)(n0 + r) * DIN)
                              : (w_ih_b + (size_t)(n0 + r - G4) * DIN);
  float acc[8][4];
#pragma unroll
  for (int m = 0; m < 8; ++m)
#pragma unroll
    for (int n = 0; n < 4; ++n) acc[m][n] = 0.f;
  __syncthreads();

  for (int it = 0; it < 75; ++it) {
    int kk = it * 16 + kq * 4;
    int seg = (kk >= 900) ? 3 : (kk >= 600) ? 2 : (kk >= 300) ? 1 : 0;
    int col = kk - seg * 300;
    int wid0 = w4[r][seg];
    int wid1 = w4[r + 64][seg];
    float4 a0 = *(const float4*)(W_emb + (size_t)wid0 * EMB + col);
    float4 a1 = *(const float4*)(W_emb + (size_t)wid1 * EMB + col);
    float4 b  = *(const float4*)(Bp + kk);
    As[kq * 4 + 0][r] = a0.x; As[kq * 4 + 1][r] = a0.y;
    As[kq * 4 + 2][r] = a0.z; As[kq * 4 + 3][r] = a0.w;
    As[kq * 4 + 0][r + 64] = a1.x; As[kq * 4 + 1][r + 64] = a1.y;
    As[kq * 4 + 2][r + 64] = a1.z; As[kq * 4 + 3][r + 64] = a1.w;
    Bs[kq * 4 + 0][r] = b.x; Bs[kq * 4 + 1][r] = b.y;
    Bs[kq * 4 + 2][r] = b.z; Bs[kq * 4 + 3][r] = b.w;
    __syncthreads();
    int ii = (tid & 15) * 8;
    int jj = (tid >> 4) * 4;
#pragma unroll
    for (int k2 = 0; k2 < 16; ++k2) {
      float4 av0 = *(const float4*)&As[k2][ii];
      float4 av1 = *(const float4*)&As[k2][ii + 4];
      float4 bv  = *(const float4*)&Bs[k2][jj];
      float a[8] = {av0.x, av0.y, av0.z, av0.w, av1.x, av1.y, av1.z, av1.w};
      float bb[4] = {bv.x, bv.y, bv.z, bv.w};
#pragma unroll
      for (int m = 0; m < 8; ++m)
#pragma unroll
        for (int n = 0; n < 4; ++n) acc[m][n] = fmaf(a[m], bb[n], acc[m][n]);
    }
    __syncthreads();
  }
  int ii = (tid & 15) * 8;
  int jj = (tid >> 4) * 4;
  float bias[4];
#pragma unroll
  for (int n = 0; n < 4; ++n) {
    int jg = n0 + jj + n;
    bias[n] = (jg < G4) ? (b_ih_f[jg] + b_hh_f[jg])
                        : (b_ih_b[jg - G4] + b_hh_b[jg - G4]);
  }
#pragma unroll
  for (int m = 0; m < 8; ++m) {
    int row = t0 + ii + m;
    float4 st = make_float4(acc[m][0] + bias[0], acc[m][1] + bias[1],
                            acc[m][2] + bias[2], acc[m][3] + bias[3]);
    *(float4*)(xg + (size_t)row * 2048 + n0 + jj) = st;
  }
}

// ---------------------------------------------------------------------------
// LSTM recurrence v6: v5 structure (one thread per gate row, 1024 threads,
// 16 waves) with the asm pins REMOVED and __launch_bounds__(1024, 1).
// Round-5 post-mortem: VGPR_Count=44 showed hipcc targeted 2 blocks/CU
// (64-VGPR cap); under that cap the "+v" pins forced a per-iteration
// scratch STORE+RELOAD of all 64 weight words (~1024 cy/SIMD/step — the
// measured 2385 cy/step minus scratch matches the ~1360 cy issue model).
// Now: min-1-block -> 128-VGPR cap, so a register-resident solution (~90
// words) is legal; if the remat heuristic still reloads weights from L2,
// that is 16 dwordx4/thread/step — 8x cheaper than the pin-scratch.
// Bit-identical trajectory vs rounds 1-5.
// ---------------------------------------------------------------------------
#define D4(W, H, A)                                         \
  A = sdot4(W.x, H.x, A); A = sdot4(W.y, H.y, A);           \
  A = sdot4(W.z, H.z, A); A = sdot4(W.w, H.w, A);

__global__ __launch_bounds__(1024, 1) void lstm_rec(
    const float* __restrict__ xg, const int* __restrict__ qw,
    const float* __restrict__ fac, float* __restrict__ hf,
    float* __restrict__ hb) {
  int dir = blockIdx.x;
  int tid = threadIdx.x;                    // gate row within direction
  __shared__ __align__(16) int hq[2][64];   // packed int8 h, double-buffered
  __shared__ float pre[G4];                 // preactivations

  const int* wp = qw + (size_t)(dir * G4 + tid) * 64;
  int4 w0 = ((const int4*)wp)[0],  w1 = ((const int4*)wp)[1];
  int4 w2 = ((const int4*)wp)[2],  w3 = ((const int4*)wp)[3];
  int4 w4_ = ((const int4*)wp)[4], w5 = ((const int4*)wp)[5];
  int4 w6 = ((const int4*)wp)[6],  w7 = ((const int4*)wp)[7];
  int4 w8 = ((const int4*)wp)[8],  w9 = ((const int4*)wp)[9];
  int4 wa = ((const int4*)wp)[10], wb = ((const int4*)wp)[11];
  int4 wc = ((const int4*)wp)[12], wd = ((const int4*)wp)[13];
  int4 we = ((const int4*)wp)[14], wf = ((const int4*)wp)[15];
  float fr = fac[dir * G4 + tid];

  int k = tid & (HID - 1);                  // hidden unit (phase-2 identity)
  float* hout = dir ? hb : hf;
  const ptrdiff_t xstep = dir ? -2048 : 2048;
  const ptrdiff_t hstep = dir ? -HID : HID;
  const float* xp = xg + (size_t)(dir ? T_LEN - 1 : 0) * 2048 + dir * G4 + tid;
  float* hp = hout + (size_t)(dir ? T_LEN - 1 : 0) * HID + k;  // in-bounds all
  float c = 0.f;
  if (tid < 64) hq[0][tid] = 0;
  __syncthreads();

  float xv = *xp;

  for (int s = 0; s < T_LEN; ++s) {
    // prefetch next step's x (coalesced, independent of h)
    float xn = 0.f;
    if (s + 1 < T_LEN) { xp += xstep; xn = *xp; }

    // full-K dot over broadcast h; 4 accumulators (int-assoc, bit-exact)
    const int4* hc = (const int4*)(&hq[s & 1][0]);
    int a0 = 0, a1 = 0, a2 = 0, a3 = 0;
    {
      int4 h0 = hc[0], h1 = hc[1], h2 = hc[2], h3 = hc[3];
      D4(w0, h0, a0) D4(w1, h1, a1) D4(w2, h2, a2) D4(w3, h3, a3)
      h0 = hc[4]; h1 = hc[5]; h2 = hc[6]; h3 = hc[7];
      D4(w4_, h0, a0) D4(w5, h1, a1) D4(w6, h2, a2) D4(w7, h3, a3)
      h0 = hc[8]; h1 = hc[9]; h2 = hc[10]; h3 = hc[11];
      D4(w8, h0, a0) D4(w9, h1, a1) D4(wa, h2, a2) D4(wb, h3, a3)
      h0 = hc[12]; h1 = hc[13]; h2 = hc[14]; h3 = hc[15];
      D4(wc, h0, a0) D4(wd, h1, a1) D4(we, h2, a2) D4(wf, h3, a3)
    }
    int a = (a0 + a1) + (a2 + a3);
    pre[tid] = xv + fr * (float)a;
    __syncthreads();  // A: all preactivations visible

    if (tid < HID) {  // waves 0-3 (one per SIMD) do the pointwise update
      float pi = pre[tid];
      float pf = pre[HID + tid];
      float pg = pre[2 * HID + tid];
      float po = pre[3 * HID + tid];
      float iv = sigm(pi), fg = sigm(pf), gv = tanh_fast(pg), ov = sigm(po);
      c = fg * c + iv * gv;
      float h = ov * tanh_fast(c);
      *hp = h;
      ((char*)(&hq[(s + 1) & 1][0]))[tid] = (char)(int)rintf(h * 127.0f);
    }
    hp += hstep;
    xv = xn;
    __syncthreads();  // B: next h buffer published; pre[] free to overwrite
  }
}

// ---------------------------------------------------------------------------
// feats[t][k] = W_tag[k] . [hf[t]; hb[t]] + b_tag[k]; one wave per (t,k).
// ---------------------------------------------------------------------------
__global__ __launch_bounds__(256) void feats_k(const float* __restrict__ W_tag,
                                               const float* __restrict__ b_tag,
                                               const float* __restrict__ hf,
                                               const float* __restrict__ hb,
                                               float* __restrict__ feats) {
  int pair = blockIdx.x * 4 + (threadIdx.x >> 6);
  int lane = threadIdx.x & 63;
  int t = pair / NTAG;
  int k = pair % NTAG;
  float s = 0.f;
#pragma unroll
  for (int i = 0; i < 4; ++i) {
    int j = i * 64 + lane;
    s = fmaf(W_tag[k * 512 + j], hf[(size_t)t * HID + j], s);
  }
#pragma unroll
  for (int i = 4; i < 8; ++i) {
    int j = i * 64 + lane;
    s = fmaf(W_tag[k * 512 + j], hb[(size_t)t * HID + (j - 256)], s);
  }
#pragma unroll
  for (int off = 32; off > 0; off >>= 1) s += __shfl_xor(s, off, 64);
  if (lane == 0) feats[t * NTAG + k] = s + b_tag[k];
}

// ---------------------------------------------------------------------------
// Viterbi: lane k (<12) holds fv[k]; strict-> ascending scans match
// jnp.argmax first-max tie semantics. Backpointers in LDS; lane-0 backtrace.
// Output: d_out[0]=score, d_out[1..4096]=path (as f32).
// ---------------------------------------------------------------------------
__global__ __launch_bounds__(64) void viterbi_k(const float* __restrict__ feats,
                                                const float* __restrict__ trans,
                                                float* __restrict__ out) {
  __shared__ unsigned char bpL[T_LEN * NTAG];
  int k = threadIdx.x;
  bool act = k < NTAG;
  float trc[NTAG];
#pragma unroll
  for (int p = 0; p < NTAG; ++p) trc[p] = act ? trans[k * NTAG + p] : NEGV;
  float fv = (act && k == START_TAG) ? 0.f : NEGV;
  float ft = act ? feats[k] : 0.f;
  for (int t = 0; t < T_LEN; ++t) {
    float ftn = (act && t + 1 < T_LEN) ? feats[(t + 1) * NTAG + k] : 0.f;
    float v[NTAG];
#pragma unroll
    for (int p = 0; p < NTAG; ++p) v[p] = __shfl(fv, p, 64) + trc[p];
    float bv = v[0];
    int bp = 0;
#pragma unroll
    for (int p = 1; p < NTAG; ++p) {
      if (v[p] > bv) { bv = v[p]; bp = p; }
    }
    if (act) {
      fv = bv + ft;
      bpL[t * NTAG + k] = (unsigned char)bp;
    }
    ft = ftn;
  }
  float term = act ? (fv + trans[STOP_TAG * NTAG + k]) : NEGV;
  if (k == START_TAG || k == STOP_TAG) term = NEGV;
  float bs = __shfl(term, 0, 64);
  int bk = 0;
#pragma unroll
  for (int p = 1; p < NTAG; ++p) {
    float vv = __shfl(term, p, 64);
    if (vv > bs) { bs = vv; bk = p; }
  }
  if (k == 0) {
    out[0] = bs;
    int cur = bk;
    for (int t = T_LEN - 1; t >= 0; --t) {
      out[1 + t] = (float)cur;
      cur = bpL[t * NTAG + cur];
    }
  }
}

// ---------------------------------------------------------------------------
extern "C" void kernel_launch(void* const* d_in, const int* in_sizes, int n_in,
                              void* d_out, int out_size, void* d_ws,
                              size_t ws_size, hipStream_t stream) {
  const int* words0 = (const int*)d_in[0];
  const int* words1 = (const int*)d_in[1];
  const int* words2 = (const int*)d_in[2];
  const int* words3 = (const int*)d_in[3];
  const float* W_emb  = (const float*)d_in[4];
  const float* w_ih_f = (const float*)d_in[5];
  const float* w_hh_f = (const float*)d_in[6];
  const float* b_ih_f = (const float*)d_in[7];
  const float* b_hh_f = (const float*)d_in[8];
  const float* w_ih_b = (const float*)d_in[9];
  const float* w_hh_b = (const float*)d_in[10];
  const float* b_ih_b = (const float*)d_in[11];
  const float* b_hh_b = (const float*)d_in[12];
  const float* W_tag  = (const float*)d_in[13];
  const float* b_tag  = (const float*)d_in[14];
  const float* trans  = (const float*)d_in[15];

  char* ws = (char*)d_ws;
  float* xg    = (float*)(ws);               // 4096*2048 f32 = 33,554,432 B
  float* hf    = (float*)(ws + 33554432);    // 4096*256 f32  =  4,194,304 B
  float* hb    = (float*)(ws + 37748736);    // 4096*256 f32  =  4,194,304 B
  int*   qw    = (int*)  (ws + 41943040);    // 2048*64 i32   =    524,288 B
  float* fac   = (float*)(ws + 42467328);    // 2048 f32
  float* feats = (float*)(ws + 42475520);    // 4096*12 f32

  quant_whh<<<dim3(2048), dim3(64), 0, stream>>>(w_hh_f, w_hh_b, qw, fac);
  xg_gemm<<<dim3(32, 32), dim3(256), 0, stream>>>(
      words0, words1, words2, words3, W_emb, w_ih_f, w_ih_b, b_ih_f, b_hh_f,
      b_ih_b, b_hh_b, xg);
  lstm_rec<<<dim3(2), dim3(1024), 0, stream>>>(xg, qw, fac, hf, hb);
  feats_k<<<dim3(12288), dim3(256), 0, stream>>>(W_tag, b_tag, hf, hb, feats);
  viterbi_k<<<dim3(1), dim3(64), 0, stream>>>(feats, trans, (float*)d_out);
}